// Round 2
// baseline (5021.174 us; speedup 1.0000x reference)
//
#include <hip/hip_runtime.h>
#include <hip/hip_bf16.h>

using u16 = unsigned short;
using u32 = unsigned int;

// ---------- helpers ----------
__device__ __forceinline__ float bf2f(u16 x){ return __uint_as_float(((u32)x)<<16); }
__device__ __forceinline__ u16 f2bf(float f){
  u32 u = __float_as_uint(f);
  u += 0x7fffu + ((u>>16)&1u);          // round-to-nearest-even
  return (u16)(u>>16);
}
__device__ __forceinline__ float rdlane(float v, int l){
  return __int_as_float(__builtin_amdgcn_readlane(__float_as_int(v), l));
}

// ---------- K1: position mixing  ctx' = ctx + (ctx_r @ Wm[h]^T + bm) ----------
// wave = (head h, 2 batch items); lane = (n_sub, ch); each lane owns one 64-token
// fp32 row (256B). Wm/bm reads are wave-uniform -> s_load. Output bf16.
__global__ __launch_bounds__(256) void k_posmix(
    const float* __restrict__ ctx, const float* __restrict__ Wm,
    const float* __restrict__ bm, u16* __restrict__ ctxp)
{
  int lane = threadIdx.x & 63;
  int wv = (blockIdx.x<<2) + (threadIdx.x>>6);            // 0..8191
  int h  = __builtin_amdgcn_readfirstlane(wv & 15);
  int np = __builtin_amdgcn_readfirstlane(wv >> 4);       // 0..511
  int n  = np*2 + (lane>>5);
  int ch = lane & 31;
  long base = (long)(n*512 + h*32 + ch) * 64;

  float cf[64];
  const float4* rp = (const float4*)(ctx + base);
  #pragma unroll
  for (int i=0;i<16;i++){
    float4 u = rp[i];
    cf[i*4+0]=u.x; cf[i*4+1]=u.y; cf[i*4+2]=u.z; cf[i*4+3]=u.w;
  }
  const float* wmh = Wm + h*4096;
  const float* bmh = bm + h*64;
  uint4* op = (uint4*)(ctxp + base);
  #pragma unroll 1
  for (int og=0; og<8; og++){
    int o0 = og*8;
    float acc[8];
    #pragma unroll
    for (int j=0;j<8;j++) acc[j] = bmh[o0+j];
    #pragma unroll
    for (int k=0;k<64;k++){
      float cv = cf[k];
      #pragma unroll
      for (int j=0;j<8;j++) acc[j] += wmh[(o0+j)*64 + k] * cv;
    }
    // residual: re-read this 32B chunk of ctx (L1 hit, avoids variable index into cf[])
    float4 r0 = rp[og*2], r1 = rp[og*2+1];
    u32 w0 = (u32)f2bf(acc[0]+r0.x) | ((u32)f2bf(acc[1]+r0.y)<<16);
    u32 w1 = (u32)f2bf(acc[2]+r0.z) | ((u32)f2bf(acc[3]+r0.w)<<16);
    u32 w2 = (u32)f2bf(acc[4]+r1.x) | ((u32)f2bf(acc[5]+r1.y)<<16);
    u32 w3 = (u32)f2bf(acc[6]+r1.z) | ((u32)f2bf(acc[7]+r1.w)<<16);
    op[og] = make_uint4(w0,w1,w2,w3);
  }
}

// ---------- K2: theta/phi/g projections (weight-stationary, SGPR broadcast) ----------
// wave = (n, tensor, 16-output chunk); lane = token x. 512-deep c loop, 16 FMA/iter.
__global__ __launch_bounds__(256) void k_proj(
    const float* __restrict__ q, const u16* __restrict__ ctxp,
    const float* __restrict__ Wt, const float* __restrict__ bt,
    const float* __restrict__ Wp, const float* __restrict__ bp,
    const float* __restrict__ Wg, const float* __restrict__ bg,
    u16* __restrict__ theta, u16* __restrict__ phi, u16* __restrict__ g)
{
  int lane = threadIdx.x & 63;
  int gw = __builtin_amdgcn_readfirstlane((blockIdx.x<<2) + (threadIdx.x>>6)); // 0..49151
  int n = gw / 48;
  int r = gw - n*48;
  int tensor = r >> 4;
  int o0 = (r & 15) << 4;
  const float* W; const float* b; u16* dst;
  if (tensor == 0)      { W = Wt; b = bt; dst = theta; }
  else if (tensor == 1) { W = Wp; b = bp; dst = phi; }
  else                  { W = Wg; b = bg; dst = g; }
  const float* Wb = W + o0*512;
  float acc[16];
  #pragma unroll
  for (int j=0;j<16;j++) acc[j] = 0.f;
  if (tensor == 0){
    const float* srow = q + (long)n*32768 + lane;         // query, fp32
    for (int c=0;c<512;c++){
      float v = srow[c*64];
      #pragma unroll
      for (int j=0;j<16;j++) acc[j] += Wb[j*512 + c] * v;
    }
  } else {
    const u16* srow = ctxp + (long)n*32768 + lane;        // mixed context, bf16
    for (int c=0;c<512;c++){
      float v = bf2f(srow[c*64]);
      #pragma unroll
      for (int j=0;j<16;j++) acc[j] += Wb[j*512 + c] * v;
    }
  }
  u16* drow = dst + (long)n*16384 + o0*64 + lane;
  #pragma unroll
  for (int j=0;j<16;j++) drow[j*64] = f2bf(acc[j] + b[o0+j]);
}

// ---------- K3: per-(n,head) attention. lane = query token q; phi/g columns held
// per-lane and broadcast with v_readlane. Scores kept in a per-wave LDS strip. ----------
__global__ __launch_bounds__(256) void k_attn(
    const u16* theta, const u16* __restrict__ phi, const u16* __restrict__ g, u16* y)
{
  __shared__ float sbuf[4*64*64];                 // 64 KB, per-wave 4096-float strip
  int lane = threadIdx.x & 63;
  int w = threadIdx.x >> 6;
  int wv = (blockIdx.x<<2) + w;                   // 0..16383
  int n = wv >> 4, h = wv & 15;
  long base = (long)n*16384 + h*1024 + lane;      // (h*16+d)*64 + q

  float th[16], ph[16], gg[16];
  #pragma unroll
  for (int d=0;d<16;d++){
    th[d] = bf2f(theta[base + d*64]);   // lane holds theta[:, q]
    ph[d] = bf2f(phi  [base + d*64]);   // lane holds phi[:, k=lane]
    gg[d] = bf2f(g    [base + d*64]);   // lane holds g[:, k=lane]
  }
  float* sl = sbuf + w*4096;
  float m = -1e30f;
  for (int k=0;k<64;k++){
    float acc = 0.f;
    #pragma unroll
    for (int d=0;d<16;d++) acc += th[d] * rdlane(ph[d], k);
    acc *= 0.25f;                        // 1/sqrt(dh), dh=16
    m = fmaxf(m, acc);
    sl[k*64 + lane] = acc;               // bank-conflict-free (lane-major)
  }
  float sum = 0.f;
  float ya[16];
  #pragma unroll
  for (int d=0;d<16;d++) ya[d] = 0.f;
  for (int k=0;k<64;k++){
    float p = __expf(sl[k*64 + lane] - m);
    sum += p;
    #pragma unroll
    for (int d=0;d<16;d++) ya[d] += p * rdlane(gg[d], k);
  }
  float inv = 1.f / sum;
  #pragma unroll
  for (int d=0;d<16;d++) y[base + d*64] = f2bf(ya[d]*inv);  // y aliases theta (consumed)
}

// ---------- K4: out = Wo @ y + bo + query (fp32 out) ----------
__global__ __launch_bounds__(256) void k_out(
    const float* __restrict__ query, const u16* __restrict__ y,
    const float* __restrict__ Wo, const float* __restrict__ bo,
    float* __restrict__ out)
{
  int lane = threadIdx.x & 63;
  int gw = __builtin_amdgcn_readfirstlane((blockIdx.x<<2) + (threadIdx.x>>6)); // 0..32767
  int n = gw >> 5;
  int o0 = (gw & 31) << 4;
  const u16* yrow = y + (long)n*16384 + lane;
  const float* Wb = Wo + o0*256;
  float acc[16];
  #pragma unroll
  for (int j=0;j<16;j++) acc[j] = 0.f;
  for (int i=0;i<256;i++){
    float v = bf2f(yrow[i*64]);
    #pragma unroll
    for (int j=0;j<16;j++) acc[j] += Wb[j*256 + i] * v;
  }
  long obase = (long)n*32768 + (long)o0*64 + lane;
  #pragma unroll
  for (int j=0;j<16;j++){
    out[obase + j*64] = acc[j] + bo[o0+j] + query[obase + j*64];
  }
}

// ---------- launch ----------
extern "C" void kernel_launch(void* const* d_in, const int* in_sizes, int n_in,
                              void* d_out, int out_size, void* d_ws, size_t ws_size,
                              hipStream_t stream)
{
  const float* query = (const float*)d_in[0];
  const float* ctx   = (const float*)d_in[1];
  const float* Wm    = (const float*)d_in[2];
  const float* bm    = (const float*)d_in[3];
  const float* Wg    = (const float*)d_in[4];
  const float* bg    = (const float*)d_in[5];
  const float* Wt    = (const float*)d_in[6];
  const float* bt    = (const float*)d_in[7];
  const float* Wp    = (const float*)d_in[8];
  const float* bp    = (const float*)d_in[9];
  const float* Wo    = (const float*)d_in[10];
  const float* bo    = (const float*)d_in[11];

  u16* ctxp   = (u16*)d_ws;                             // [1024][512][64] bf16, 64MB
  u16* theta  = ctxp + 33554432;                        // [1024][256][64] bf16, 32MB
  u16* phi    = theta + 16777216;
  u16* gbuf   = phi + 16777216;
  u16* ybuf   = theta;                                  // alias: theta consumed before y write
  float* outp = (float*)d_out;

  hipLaunchKernelGGL(k_posmix, dim3(2048), dim3(256), 0, stream, ctx, Wm, bm, ctxp);
  hipLaunchKernelGGL(k_proj,   dim3(12288), dim3(256), 0, stream,
                     query, ctxp, Wt, bt, Wp, bp, Wg, bg, theta, phi, gbuf);
  hipLaunchKernelGGL(k_attn,   dim3(4096), dim3(256), 0, stream, theta, phi, gbuf, ybuf);
  hipLaunchKernelGGL(k_out,    dim3(8192), dim3(256), 0, stream, query, ybuf, Wo, bo, outp);
}

// Round 3
// 730.338 us; speedup vs baseline: 6.8751x; 6.8751x over previous
//
#include <hip/hip_runtime.h>
#include <hip/hip_bf16.h>

using u16 = unsigned short;
using u32 = unsigned int;
typedef __attribute__((ext_vector_type(8))) short short8;
typedef __attribute__((ext_vector_type(4))) float f32x4;

// ---------- helpers ----------
__device__ __forceinline__ float bf2f(u16 x){ return __uint_as_float(((u32)x)<<16); }
__device__ __forceinline__ u16 f2bf(float f){
  u32 u = __float_as_uint(f);
  u += 0x7fffu + ((u>>16)&1u);          // round-to-nearest-even
  return (u16)(u>>16);
}
__device__ __forceinline__ float rdlane(float v, int l){
  return __int_as_float(__builtin_amdgcn_readlane(__float_as_int(v), l));
}
__device__ __forceinline__ short8 pack8(float4 a, float4 b){
  union { short8 s; u32 u[4]; } r;
  r.u[0] = (u32)f2bf(a.x) | ((u32)f2bf(a.y)<<16);
  r.u[1] = (u32)f2bf(a.z) | ((u32)f2bf(a.w)<<16);
  r.u[2] = (u32)f2bf(b.x) | ((u32)f2bf(b.y)<<16);
  r.u[3] = (u32)f2bf(b.z) | ((u32)f2bf(b.w)<<16);
  return r.s;
}
#define MFMA(a,b,c) __builtin_amdgcn_mfma_f32_16x16x32_bf16((a),(b),(c),0,0,0)

// ws layout (u16 offsets): Wt_b 0, Wp_b 131072, Wg_b 262144, Wo_b 393216,
// Wm_b 524288, end 589824. ctxp at 589824 (33554432), theta/phi/g follow.
// yT aliases ctxp (dead after k_proj). Total ~161 MB.

// ---------- K0: weights fp32 -> bf16 ----------
__global__ __launch_bounds__(256) void k_prep(
    const float* __restrict__ Wt, const float* __restrict__ Wp,
    const float* __restrict__ Wg, const float* __restrict__ Wo,
    const float* __restrict__ Wm, u16* __restrict__ wb)
{
  int i8 = (blockIdx.x*256 + threadIdx.x)*8;
  const float* src; int local;
  if      (i8 < 131072){ src = Wt; local = i8; }
  else if (i8 < 262144){ src = Wp; local = i8-131072; }
  else if (i8 < 393216){ src = Wg; local = i8-262144; }
  else if (i8 < 524288){ src = Wo; local = i8-393216; }
  else                 { src = Wm; local = i8-524288; }
  float4 a = *(const float4*)(src+local);
  float4 b = *(const float4*)(src+local+4);
  union { short8 s; uint4 u; } r;
  r.s = pack8(a,b);
  *(uint4*)(wb + i8) = r.u;
}

// ---------- K1: position mixing via MFMA ----------
// wave = (n,h). C[d(32) x o(64)] = ctx_slice(32x64) x Wm[h]^T(64x64), K=64.
// epilogue: + bm[h][o] + ctx residual -> ctxp bf16 [n][c][x].
__global__ __launch_bounds__(256) void k_posmix(
    const float* __restrict__ ctx, const u16* __restrict__ wm_b,
    const float* __restrict__ bm, u16* __restrict__ ctxp)
{
  int lane = threadIdx.x & 63;
  int l15 = lane & 15, q = lane >> 4;
  int wv = (blockIdx.x<<2) + (threadIdx.x>>6);     // 0..16383
  int n = wv >> 4, h = wv & 15;
  const float* cbase = ctx + (size_t)n*32768 + h*2048;   // ctx[n][h*32][0]
  const u16*  wmb   = wm_b + h*4096;
  f32x4 acc[2][4];
  #pragma unroll
  for (int mi=0;mi<2;mi++)
    #pragma unroll
    for (int ni=0;ni<4;ni++) acc[mi][ni] = (f32x4){0.f,0.f,0.f,0.f};

  #pragma unroll
  for (int ks=0; ks<2; ks++){
    short8 a[2], b[4];
    #pragma unroll
    for (int mi=0; mi<2; mi++){
      const float* ap = cbase + (mi*16 + l15)*64 + ks*32 + q*8;
      float4 v0 = *(const float4*)ap;
      float4 v1 = *(const float4*)(ap+4);
      a[mi] = pack8(v0, v1);
    }
    #pragma unroll
    for (int ni=0; ni<4; ni++)
      b[ni] = *(const short8*)(wmb + (ni*16 + l15)*64 + ks*32 + q*8);
    #pragma unroll
    for (int mi=0;mi<2;mi++)
      #pragma unroll
      for (int ni=0;ni<4;ni++) acc[mi][ni] = MFMA(a[mi], b[ni], acc[mi][ni]);
  }

  float bmv[4];
  #pragma unroll
  for (int ni=0;ni<4;ni++) bmv[ni] = bm[h*64 + ni*16 + l15];
  u16* obase = ctxp + (size_t)n*32768 + h*2048;
  #pragma unroll
  for (int mi=0;mi<2;mi++)
    #pragma unroll
    for (int r=0;r<4;r++){
      int row = mi*16 + q*4 + r;                   // d in [0,32)
      #pragma unroll
      for (int ni=0;ni<4;ni++){
        int col = ni*16 + l15;
        float res = cbase[row*64 + col];
        obase[row*64 + col] = f2bf(acc[mi][ni][r] + bmv[ni] + res);
      }
    }
}

// ---------- K2: theta/phi/g projections via MFMA ----------
// block = (n, tensor). C[256 o x 64 x] = W(256x512) x S(512x64), K=512.
// S staged per 32-K slice into LDS transposed ([x][kc], stride 44 u16):
// conflict-free ds_read_b64 B-frags; A-frags stream from bf16 weights (L2-hot).
__global__ __launch_bounds__(256) void k_proj(
    const float* __restrict__ query, const u16* __restrict__ ctxp,
    const u16* __restrict__ wb, const float* __restrict__ bt,
    const float* __restrict__ bp, const float* __restrict__ bg,
    u16* __restrict__ theta, u16* __restrict__ phi, u16* __restrict__ g)
{
  __shared__ u16 sb[64*44 + 16];
  int t = threadIdx.x;
  int lane = t & 63, l15 = lane & 15, q = lane >> 4, w = t >> 6;
  int n = blockIdx.x, tensor = blockIdx.y;
  const u16* W = wb + tensor*131072;
  const float* bias = (tensor==0) ? bt : (tensor==1) ? bp : bg;
  u16* dst = (tensor==0) ? theta : (tensor==1) ? phi : g;

  f32x4 acc[4][4];
  #pragma unroll
  for (int mi=0;mi<4;mi++)
    #pragma unroll
    for (int ni=0;ni<4;ni++) acc[mi][ni] = (f32x4){0.f,0.f,0.f,0.f};

  int sc = (t>>4)*2;          // c-pair base (0..30)
  int sx = (t&15)*4;          // x base (0..60)

  for (int ks=0; ks<16; ks++){
    int k0 = ks*32;
    // ---- stage S[k0..k0+32)[0..64) -> sb[x*44 + kc] (bf16, transposed) ----
    if (tensor == 0){
      const float* s0 = query + (size_t)n*32768 + (size_t)(k0+sc)*64 + sx;
      float4 va = *(const float4*)s0;
      float4 vb = *(const float4*)(s0 + 64);
      *(u32*)&sb[(sx+0)*44 + sc] = (u32)f2bf(va.x) | ((u32)f2bf(vb.x)<<16);
      *(u32*)&sb[(sx+1)*44 + sc] = (u32)f2bf(va.y) | ((u32)f2bf(vb.y)<<16);
      *(u32*)&sb[(sx+2)*44 + sc] = (u32)f2bf(va.z) | ((u32)f2bf(vb.z)<<16);
      *(u32*)&sb[(sx+3)*44 + sc] = (u32)f2bf(va.w) | ((u32)f2bf(vb.w)<<16);
    } else {
      const u16* s0 = ctxp + (size_t)n*32768 + (size_t)(k0+sc)*64 + sx;
      uint2 ua = *(const uint2*)s0;
      uint2 ub = *(const uint2*)(s0 + 64);
      *(u32*)&sb[(sx+0)*44 + sc] = (ua.x & 0xffffu) | ((ub.x & 0xffffu)<<16);
      *(u32*)&sb[(sx+1)*44 + sc] = (ua.x >> 16)     | (ub.x & 0xffff0000u);
      *(u32*)&sb[(sx+2)*44 + sc] = (ua.y & 0xffffu) | ((ub.y & 0xffffu)<<16);
      *(u32*)&sb[(sx+3)*44 + sc] = (ua.y >> 16)     | (ub.y & 0xffff0000u);
    }
    __syncthreads();
    // ---- compute ----
    short8 a[4], b[4];
    #pragma unroll
    for (int mi=0;mi<4;mi++)
      a[mi] = *(const short8*)(W + (size_t)(w*64 + mi*16 + l15)*512 + k0 + q*8);
    #pragma unroll
    for (int ni=0;ni<4;ni++){
      union { short8 s; uint2 u[2]; } bb;
      int bidx = (ni*16 + l15)*44 + q*8;
      bb.u[0] = *(const uint2*)&sb[bidx];
      bb.u[1] = *(const uint2*)&sb[bidx + 4];
      b[ni] = bb.s;
    }
    #pragma unroll
    for (int mi=0;mi<4;mi++)
      #pragma unroll
      for (int ni=0;ni<4;ni++) acc[mi][ni] = MFMA(a[mi], b[ni], acc[mi][ni]);
    __syncthreads();
  }

  u16* dbase = dst + (size_t)n*16384;
  #pragma unroll
  for (int mi=0;mi<4;mi++)
    #pragma unroll
    for (int r=0;r<4;r++){
      int row = w*64 + mi*16 + q*4 + r;
      float bv = bias[row];
      #pragma unroll
      for (int ni=0;ni<4;ni++){
        int col = ni*16 + l15;
        dbase[row*64 + col] = f2bf(acc[mi][ni][r] + bv);
      }
    }
}

// ---------- K3: attention (per n,head). Writes yT[n][x][i] (x-major). ----------
__global__ __launch_bounds__(256) void k_attn(
    const u16* __restrict__ theta, const u16* __restrict__ phi,
    const u16* __restrict__ g, u16* __restrict__ yT)
{
  __shared__ float sbuf[4*64*64];                 // per-wave 4096-float strip
  int lane = threadIdx.x & 63;
  int w = threadIdx.x >> 6;
  int wv = (blockIdx.x<<2) + w;                   // 0..16383
  int n = wv >> 4, h = wv & 15;
  size_t base = (size_t)n*16384 + h*1024 + lane;  // (h*16+d)*64 + q

  float th[16], ph[16], gg[16];
  #pragma unroll
  for (int d=0;d<16;d++){
    th[d] = bf2f(theta[base + d*64]);
    ph[d] = bf2f(phi  [base + d*64]);
    gg[d] = bf2f(g    [base + d*64]);
  }
  float* sl = sbuf + w*4096;
  float m = -1e30f;
  for (int k=0;k<64;k++){
    float acc = 0.f;
    #pragma unroll
    for (int d=0;d<16;d++) acc += th[d] * rdlane(ph[d], k);
    acc *= 0.25f;
    m = fmaxf(m, acc);
    sl[k*64 + lane] = acc;
  }
  float sum = 0.f;
  float ya[16];
  #pragma unroll
  for (int d=0;d<16;d++) ya[d] = 0.f;
  for (int k=0;k<64;k++){
    float p = __expf(sl[k*64 + lane] - m);
    sum += p;
    #pragma unroll
    for (int d=0;d<16;d++) ya[d] += p * rdlane(gg[d], k);
  }
  float inv = 1.f / sum;
  u32 pk[8];
  #pragma unroll
  for (int j=0;j<8;j++)
    pk[j] = (u32)f2bf(ya[2*j]*inv) | ((u32)f2bf(ya[2*j+1]*inv)<<16);
  uint4* yp = (uint4*)(yT + (size_t)n*16384 + (size_t)lane*256 + h*16);
  yp[0] = make_uint4(pk[0],pk[1],pk[2],pk[3]);
  yp[1] = make_uint4(pk[4],pk[5],pk[6],pk[7]);
}

// ---------- K4: out = Wo @ y + bo + query via MFMA ----------
// block = (n, half). C[256 o x 64 x], K=256. B-frags direct from yT (L1-hot).
__global__ __launch_bounds__(256) void k_out(
    const float* __restrict__ query, const u16* __restrict__ yT,
    const u16* __restrict__ wo_b, const float* __restrict__ bo,
    float* __restrict__ out)
{
  int t = threadIdx.x, lane = t & 63, l15 = lane & 15, q = lane >> 4, w = t >> 6;
  int n = blockIdx.x;
  int mbase = blockIdx.y*256 + w*64;
  f32x4 acc[4][4];
  #pragma unroll
  for (int mi=0;mi<4;mi++)
    #pragma unroll
    for (int ni=0;ni<4;ni++) acc[mi][ni] = (f32x4){0.f,0.f,0.f,0.f};

  #pragma unroll 2
  for (int ks=0; ks<8; ks++){
    int k0 = ks*32;
    short8 a[4], b[4];
    #pragma unroll
    for (int mi=0;mi<4;mi++)
      a[mi] = *(const short8*)(wo_b + (size_t)(mbase + mi*16 + l15)*256 + k0 + q*8);
    #pragma unroll
    for (int ni=0;ni<4;ni++)
      b[ni] = *(const short8*)(yT + (size_t)n*16384 + (size_t)(ni*16 + l15)*256 + k0 + q*8);
    #pragma unroll
    for (int mi=0;mi<4;mi++)
      #pragma unroll
      for (int ni=0;ni<4;ni++) acc[mi][ni] = MFMA(a[mi], b[ni], acc[mi][ni]);
  }

  #pragma unroll
  for (int mi=0;mi<4;mi++)
    #pragma unroll
    for (int r=0;r<4;r++){
      int row = mbase + mi*16 + q*4 + r;
      float bv = bo[row];
      #pragma unroll
      for (int ni=0;ni<4;ni++){
        int col = ni*16 + l15;
        size_t idx = (size_t)n*32768 + (size_t)row*64 + col;
        out[idx] = acc[mi][ni][r] + bv + query[idx];
      }
    }
}

// ---------- launch ----------
extern "C" void kernel_launch(void* const* d_in, const int* in_sizes, int n_in,
                              void* d_out, int out_size, void* d_ws, size_t ws_size,
                              hipStream_t stream)
{
  const float* query = (const float*)d_in[0];
  const float* ctx   = (const float*)d_in[1];
  const float* Wm    = (const float*)d_in[2];
  const float* bm    = (const float*)d_in[3];
  const float* Wg    = (const float*)d_in[4];
  const float* bg    = (const float*)d_in[5];
  const float* Wt    = (const float*)d_in[6];
  const float* bt    = (const float*)d_in[7];
  const float* Wp    = (const float*)d_in[8];
  const float* bp    = (const float*)d_in[9];
  const float* Wo    = (const float*)d_in[10];
  const float* bo    = (const float*)d_in[11];

  u16* wb    = (u16*)d_ws;                 // bf16 weights: 589824 u16
  u16* ctxp  = wb + 589824;                // [1024][512][64] bf16
  u16* theta = ctxp + 33554432;            // [1024][256][64] bf16
  u16* phi   = theta + 16777216;
  u16* g     = phi + 16777216;
  u16* yTb   = ctxp;                       // alias: ctxp dead after k_proj
  float* outp = (float*)d_out;

  hipLaunchKernelGGL(k_prep,   dim3(288),     dim3(256), 0, stream, Wt,Wp,Wg,Wo,Wm, wb);
  hipLaunchKernelGGL(k_posmix, dim3(4096),    dim3(256), 0, stream, ctx, wb+524288, bm, ctxp);
  hipLaunchKernelGGL(k_proj,   dim3(1024,3),  dim3(256), 0, stream,
                     query, ctxp, wb, bt, bp, bg, theta, phi, g);
  hipLaunchKernelGGL(k_attn,   dim3(4096),    dim3(256), 0, stream, theta, phi, g, yTb);
  hipLaunchKernelGGL(k_out,    dim3(1024,2),  dim3(256), 0, stream, query, yTb, wb+393216, bo, outp);
}